// Round 1
// baseline (465.773 us; speedup 1.0000x reference)
//
#include <hip/hip_runtime.h>
#include <stdint.h>

// Problem constants (fixed by reference setup_inputs).
#define N_REF   500000
#define N_PC    128
#define N_FEAT  2000
#define TOPK    16

#define K1_BLOCKS  2048
#define K1_THREADS 256
#define K1_WAVES   (K1_BLOCKS * (K1_THREADS / 64))   // 8192 waves
#define N_PAIRS    (N_REF / 2)                        // 250000 row-pairs
#define NCAND      (K1_BLOCKS * TOPK)                 // 32768 candidates

typedef unsigned long long u64;

// ---------------------------------------------------------------------------
// Branchless insert of x into ascending sorted top[0..15] (drops the max).
// Static indices only -> stays in registers (SGPRs when x is wave-uniform).
__device__ __forceinline__ void insert16(u64* top, u64 x) {
#pragma unroll
    for (int i = 15; i >= 1; --i) {
        u64 lo = top[i - 1];
        u64 hi = (x > lo) ? x : lo;            // max(old top[i-1], x)
        top[i] = (top[i] < hi) ? top[i] : hi;  // min(old top[i], hi)
    }
    top[0] = (top[0] < x) ? top[0] : x;
}

// Bitonic sort of 64 values across the 64 lanes of a wave (ascending).
__device__ __forceinline__ u64 bitonic_sort64(u64 v, int lane) {
#pragma unroll
    for (int k = 2; k <= 64; k <<= 1) {
#pragma unroll
        for (int j = k >> 1; j >= 1; j >>= 1) {
            u64 o = __shfl_xor(v, j);
            bool up    = ((lane & k) == 0);
            bool lower = ((lane & j) == 0);
            u64 mn = (v < o) ? v : o;
            u64 mx = (v < o) ? o : v;
            v = (up == lower) ? mn : mx;
        }
    }
    return v;
}

// ---------------------------------------------------------------------------
// k0: partial projection. 16 blocks x 128 threads; block b handles features
// [125b, 125(b+1)). part[b][p] = sum_f din[f] * T[f][p].
__global__ void proj_partial(const float* __restrict__ din,
                             const float* __restrict__ T,
                             float* __restrict__ part) {
    int b = blockIdx.x;    // 0..15
    int t = threadIdx.x;   // 0..127
    int f0 = b * 125;
    float acc = 0.f;
#pragma unroll 5
    for (int f = f0; f < f0 + 125; ++f)
        acc += din[f] * T[(size_t)f * 128 + t];
    part[b * 128 + t] = acc;
}

// ---------------------------------------------------------------------------
// k1: L1 distances + per-block top-16. One wave processes 2 rows per iter:
// lanes 0-31 hold row0's 128 floats as float4, lanes 32-63 row1's.
__global__ __launch_bounds__(K1_THREADS) void dist_topk(
        const float* __restrict__ part,
        const float* __restrict__ ref,
        u64* __restrict__ cand) {
    __shared__ __align__(16) float pc[N_PC];
    __shared__ u64 wl[64];

    int tid  = threadIdx.x;
    int lane = tid & 63;
    int w    = tid >> 6;   // wave in block, 0..3

    if (tid < N_PC) {
        float s = 0.f;
#pragma unroll
        for (int b = 0; b < 16; ++b) s += part[b * N_PC + tid];
        pc[tid] = s;
    }
    __syncthreads();

    // Each lane's 4 query components (fixed for the whole loop).
    float4 qv = reinterpret_cast<const float4*>(pc)[lane & 31];

    u64 top[TOPK];
#pragma unroll
    for (int i = 0; i < TOPK; ++i) top[i] = ~0ull;

    int gw = blockIdx.x * (K1_THREADS / 64) + w;
    const float4* ref4 = reinterpret_cast<const float4*>(ref);

    for (int pair = gw; pair < N_PAIRS; pair += K1_WAVES) {
        float4 v = ref4[(size_t)pair * 64 + lane];   // 1 KB per wave, coalesced
        float d = fabsf(qv.x - v.x) + fabsf(qv.y - v.y)
                + fabsf(qv.z - v.z) + fabsf(qv.w - v.w);
        // Reduce within each 32-lane half simultaneously.
#pragma unroll
        for (int off = 16; off >= 1; off >>= 1)
            d += __shfl_xor(d, off);
        // Pull both row-distances to SGPRs -> top-16 maintenance on SALU.
        unsigned b0 = (unsigned)__builtin_amdgcn_readlane(__float_as_int(d), 0);
        unsigned b1 = (unsigned)__builtin_amdgcn_readlane(__float_as_int(d), 32);
        u64 k0 = (((u64)b0) << 32) | (u64)(2u * (unsigned)pair);
        u64 k1 = (((u64)b1) << 32) | (u64)(2u * (unsigned)pair + 1u);
        if (k0 < top[TOPK - 1]) insert16(top, k0);   // wave-uniform branch
        if (k1 < top[TOPK - 1]) insert16(top, k1);
    }

    // Dump each wave's (uniform) top-16 to LDS from lane 0, static indices.
    if (lane == 0) {
#pragma unroll
        for (int i = 0; i < TOPK; ++i) wl[w * TOPK + i] = top[i];
    }
    __syncthreads();

    // Wave 0 merges 4x16 candidates -> block top-16 via bitonic sort.
    if (tid < 64) {
        u64 v = bitonic_sort64(wl[tid], tid);
        if (tid < TOPK) cand[blockIdx.x * TOPK + tid] = v;
    }
}

// ---------------------------------------------------------------------------
// k2: merge 32768 candidates -> global top-16 -> mean(psuedo[idx]).
__global__ __launch_bounds__(256) void final_topk(
        const u64* __restrict__ cand,
        const float* __restrict__ psuedo,
        float* __restrict__ out) {
    __shared__ u64 wl[64];
    int tid  = threadIdx.x;
    int lane = tid & 63;
    int w    = tid >> 6;

    u64 top[TOPK];
#pragma unroll
    for (int i = 0; i < TOPK; ++i) top[i] = ~0ull;

    for (int i = tid; i < NCAND; i += 256) {
        u64 x = cand[i];
        if (x < top[TOPK - 1]) insert16(top, x);   // per-lane, divergent: ok
    }

    // Per-wave: merge 64 sorted per-lane lists -> wave top-16.
    // Keys are globally unique (row idx in low bits), so argmin is unique.
    u64 chosen = 0;
#pragma unroll
    for (int r = 0; r < TOPK; ++r) {
        u64 m = top[0];
#pragma unroll
        for (int off = 32; off >= 1; off >>= 1) {
            u64 o = __shfl_xor(m, off);
            m = (o < m) ? o : m;
        }
        if (top[0] == m) {          // exactly one lane pops
#pragma unroll
            for (int i = 0; i < TOPK - 1; ++i) top[i] = top[i + 1];
            top[TOPK - 1] = ~0ull;
        }
        if (lane == r) chosen = m;
    }
    if (lane < TOPK) wl[w * TOPK + lane] = chosen;
    __syncthreads();

    // Wave 0: 4x16 -> global top-16, gather psuedo, mean.
    if (tid < 64) {
        u64 v = bitonic_sort64(wl[tid], tid);
        float p = 0.f;
        if (tid < TOPK) p = psuedo[(unsigned)(v & 0xffffffffull)];
#pragma unroll
        for (int off = 32; off >= 1; off >>= 1)
            p += __shfl_xor(p, off);
        if (tid == 0) out[0] = p * (1.0f / (float)TOPK);
    }
}

// ---------------------------------------------------------------------------
extern "C" void kernel_launch(void* const* d_in, const int* in_sizes, int n_in,
                              void* d_out, int out_size, void* d_ws, size_t ws_size,
                              hipStream_t stream) {
    const float* din = (const float*)d_in[0];   // [1, 2000]
    const float* T   = (const float*)d_in[1];   // [2000, 128]
    const float* ref = (const float*)d_in[2];   // [500000, 128]
    const float* ps  = (const float*)d_in[3];   // [500000]
    // d_in[4] is K == 16, baked in as TOPK.

    float* part = (float*)d_ws;                           // 16*128 floats = 8 KB
    u64*   cand = (u64*)((char*)d_ws + 8192);             // 32768 * 8 B = 256 KB
    float* outp = (float*)d_out;

    proj_partial<<<16, 128, 0, stream>>>(din, T, part);
    dist_topk<<<K1_BLOCKS, K1_THREADS, 0, stream>>>(part, ref, cand);
    final_topk<<<1, 256, 0, stream>>>(cand, ps, outp);
}

// Round 2
// 394.110 us; speedup vs baseline: 1.1818x; 1.1818x over previous
//
#include <hip/hip_runtime.h>
#include <stdint.h>

// Problem constants (fixed by reference setup_inputs).
#define N_REF   500000
#define N_PC    128
#define N_FEAT  2000
#define TOPK    16

#define K1_BLOCKS  2048
#define K1_THREADS 256
#define K1_WAVES   (K1_BLOCKS * (K1_THREADS / 64))   // 8192 waves
#define N_QUAD     (N_REF / 4)                        // 125000 row-quads

#define PROJ_BLOCKS 40                                // 2000 = 40 * 50
#define FEAT_PER_BLK 50

#define K2_BLOCKS  128
#define NCAND      (K2_BLOCKS * TOPK)                 // 2048 candidates

typedef unsigned long long u64;

// ---------------------------------------------------------------------------
// Branchless insert of x into ascending sorted top[0..15] (drops the max).
__device__ __forceinline__ void insert16(u64* top, u64 x) {
#pragma unroll
    for (int i = 15; i >= 1; --i) {
        u64 lo = top[i - 1];
        u64 hi = (x > lo) ? x : lo;            // max(old top[i-1], x)
        top[i] = (top[i] < hi) ? top[i] : hi;  // min(old top[i], hi)
    }
    top[0] = (top[0] < x) ? top[0] : x;
}

// Bitonic sort of 64 values across the 64 lanes of a wave (ascending).
__device__ __forceinline__ u64 bitonic_sort64(u64 v, int lane) {
#pragma unroll
    for (int k = 2; k <= 64; k <<= 1) {
#pragma unroll
        for (int j = k >> 1; j >= 1; j >>= 1) {
            u64 o = __shfl_xor(v, j);
            bool up    = ((lane & k) == 0);
            bool lower = ((lane & j) == 0);
            u64 mn = (v < o) ? v : o;
            u64 mx = (v < o) ? o : v;
            v = (up == lower) ? mn : mx;
        }
    }
    return v;
}

// ---------------------------------------------------------------------------
// k0: partial projection. 40 blocks x 128 threads; block b handles features
// [50b, 50(b+1)). part[b][p] = sum_f din[f] * T[f][p].
__global__ void proj_partial(const float* __restrict__ din,
                             const float* __restrict__ T,
                             float* __restrict__ part) {
    int b = blockIdx.x;    // 0..39
    int t = threadIdx.x;   // 0..127
    int f0 = b * FEAT_PER_BLK;
    float acc = 0.f;
#pragma unroll 10
    for (int i = 0; i < FEAT_PER_BLK; ++i) {
        int f = f0 + i;
        acc += din[f] * T[(size_t)f * N_PC + t];
    }
    part[b * N_PC + t] = acc;
}

// ---------------------------------------------------------------------------
// k1: pure distance stream. Branch-free hot loop: one wave handles 4 rows per
// iteration via two independent float4 loads (2 KB/wave/iter) + two
// independent butterfly-reduction chains. Writes dist[N_REF] (2 MB).
__global__ __launch_bounds__(K1_THREADS) void dist_stream(
        const float* __restrict__ part,
        const float* __restrict__ ref,
        float* __restrict__ dist) {
    __shared__ __align__(16) float pc[N_PC];

    int tid  = threadIdx.x;
    int lane = tid & 63;
    int w    = tid >> 6;   // wave in block, 0..3

    if (tid < N_PC) {
        float s = 0.f;
#pragma unroll
        for (int b = 0; b < PROJ_BLOCKS; ++b) s += part[b * N_PC + tid];
        pc[tid] = s;
    }
    __syncthreads();

    // Each lane's 4 query components (fixed for the whole loop).
    float4 qv = reinterpret_cast<const float4*>(pc)[lane & 31];

    int gw = blockIdx.x * (K1_THREADS / 64) + w;
    const float4* ref4 = reinterpret_cast<const float4*>(ref);

    for (int g = gw; g < N_QUAD; g += K1_WAVES) {
        size_t base = (size_t)g * 128;            // 4 rows = 128 float4
        float4 va = ref4[base + lane];            // rows 4g, 4g+1
        float4 vb = ref4[base + 64 + lane];       // rows 4g+2, 4g+3
        float d0 = fabsf(qv.x - va.x) + fabsf(qv.y - va.y)
                 + fabsf(qv.z - va.z) + fabsf(qv.w - va.w);
        float d1 = fabsf(qv.x - vb.x) + fabsf(qv.y - vb.y)
                 + fabsf(qv.z - vb.z) + fabsf(qv.w - vb.w);
        // xor offsets <=16 stay within each 32-lane half: lanes 0..31 end
        // with row (4g+0 / 4g+2) sums, lanes 32..63 with (4g+1 / 4g+3).
#pragma unroll
        for (int off = 16; off >= 1; off >>= 1) {
            d0 += __shfl_xor(d0, off);
            d1 += __shfl_xor(d1, off);
        }
        if ((lane & 31) == 0) {
            int half = lane >> 5;                 // 0 or 1
            dist[4 * g + half]     = d0;
            dist[4 * g + 2 + half] = d1;
        }
    }
}

// ---------------------------------------------------------------------------
// k2: top-16 over dist[N_REF] (2 MB). Per-lane insert16 on packed keys
// (dist>=0 so float bits preserve order), wave min-pop merge, block bitonic.
__global__ __launch_bounds__(256) void topk_dist(
        const float* __restrict__ dist,
        u64* __restrict__ cand) {
    __shared__ u64 wl[64];
    int tid  = threadIdx.x;
    int lane = tid & 63;
    int w    = tid >> 6;

    u64 top[TOPK];
#pragma unroll
    for (int i = 0; i < TOPK; ++i) top[i] = ~0ull;

    for (int i = blockIdx.x * 256 + tid; i < N_REF; i += K2_BLOCKS * 256) {
        u64 key = (((u64)(unsigned)__float_as_int(dist[i])) << 32) | (unsigned)i;
        if (key < top[TOPK - 1]) insert16(top, key);
    }

    // Per-wave: 16-round min-pop merge of 64 sorted lists (keys unique).
    u64 chosen = 0;
#pragma unroll
    for (int r = 0; r < TOPK; ++r) {
        u64 m = top[0];
#pragma unroll
        for (int off = 32; off >= 1; off >>= 1) {
            u64 o = __shfl_xor(m, off);
            m = (o < m) ? o : m;
        }
        if (top[0] == m) {          // exactly one lane pops
#pragma unroll
            for (int i = 0; i < TOPK - 1; ++i) top[i] = top[i + 1];
            top[TOPK - 1] = ~0ull;
        }
        if (lane == r) chosen = m;
    }
    if (lane < TOPK) wl[w * TOPK + lane] = chosen;
    __syncthreads();

    if (tid < 64) {
        u64 v = bitonic_sort64(wl[tid], tid);
        if (tid < TOPK) cand[blockIdx.x * TOPK + tid] = v;
    }
}

// ---------------------------------------------------------------------------
// k3: merge NCAND candidates -> global top-16 -> mean(psuedo[idx]).
__global__ __launch_bounds__(256) void final_topk(
        const u64* __restrict__ cand,
        const float* __restrict__ psuedo,
        float* __restrict__ out) {
    __shared__ u64 wl[64];
    int tid  = threadIdx.x;
    int lane = tid & 63;
    int w    = tid >> 6;

    u64 top[TOPK];
#pragma unroll
    for (int i = 0; i < TOPK; ++i) top[i] = ~0ull;

    for (int i = tid; i < NCAND; i += 256) {
        u64 x = cand[i];
        if (x < top[TOPK - 1]) insert16(top, x);
    }

    u64 chosen = 0;
#pragma unroll
    for (int r = 0; r < TOPK; ++r) {
        u64 m = top[0];
#pragma unroll
        for (int off = 32; off >= 1; off >>= 1) {
            u64 o = __shfl_xor(m, off);
            m = (o < m) ? o : m;
        }
        if (top[0] == m) {
#pragma unroll
            for (int i = 0; i < TOPK - 1; ++i) top[i] = top[i + 1];
            top[TOPK - 1] = ~0ull;
        }
        if (lane == r) chosen = m;
    }
    if (lane < TOPK) wl[w * TOPK + lane] = chosen;
    __syncthreads();

    if (tid < 64) {
        u64 v = bitonic_sort64(wl[tid], tid);
        float p = 0.f;
        if (tid < TOPK) p = psuedo[(unsigned)(v & 0xffffffffull)];
#pragma unroll
        for (int off = 32; off >= 1; off >>= 1)
            p += __shfl_xor(p, off);
        if (tid == 0) out[0] = p * (1.0f / (float)TOPK);
    }
}

// ---------------------------------------------------------------------------
extern "C" void kernel_launch(void* const* d_in, const int* in_sizes, int n_in,
                              void* d_out, int out_size, void* d_ws, size_t ws_size,
                              hipStream_t stream) {
    const float* din = (const float*)d_in[0];   // [1, 2000]
    const float* T   = (const float*)d_in[1];   // [2000, 128]
    const float* ref = (const float*)d_in[2];   // [500000, 128]
    const float* ps  = (const float*)d_in[3];   // [500000]
    // d_in[4] is K == 16, baked in as TOPK.

    float* part = (float*)d_ws;                                   // 40*128*4 = 20 KB
    float* dist = (float*)((char*)d_ws + 32768);                  // 500000*4 = 2 MB
    u64*   cand = (u64*)((char*)d_ws + 32768 + N_REF * 4);        // 2048*8 = 16 KB
    float* outp = (float*)d_out;

    proj_partial<<<PROJ_BLOCKS, 128, 0, stream>>>(din, T, part);
    dist_stream<<<K1_BLOCKS, K1_THREADS, 0, stream>>>(part, ref, dist);
    topk_dist<<<K2_BLOCKS, 256, 0, stream>>>(dist, cand);
    final_topk<<<1, 256, 0, stream>>>(cand, ps, outp);
}